// Round 11
// baseline (1511.399 us; speedup 1.0000x reference)
//
#include <hip/hip_runtime.h>
#include <math.h>

typedef unsigned short u16;
typedef short bf16x8 __attribute__((ext_vector_type(8)));
typedef float f32x4 __attribute__((ext_vector_type(4)));

__device__ __forceinline__ u16 f2b(float x) {
    unsigned u = __builtin_bit_cast(unsigned, x);
    unsigned r = u + 0x7fffu + ((u >> 16) & 1u);
    return (u16)(r >> 16);
}
__device__ __forceinline__ float b2f(u16 v) {
    return __builtin_bit_cast(float, (unsigned)v << 16);
}
__device__ __forceinline__ void gl_lds16(const u16* g, u16* l) {
    __builtin_amdgcn_global_load_lds(
        (const __attribute__((address_space(1))) unsigned int*)g,
        (__attribute__((address_space(3))) unsigned int*)l, 16, 0, 0);
}
__device__ __forceinline__ float wred_sum(float v) {
#pragma unroll
    for (int o = 32; o > 0; o >>= 1) v += __shfl_down(v, o, 64);
    return v;
}
__device__ __forceinline__ float wred_max(float v) {
#pragma unroll
    for (int o = 32; o > 0; o >>= 1) v = fmaxf(v, __shfl_down(v, o, 64));
    return v;
}

// ================= bf16 MFMA GEMM (NT): C[M][N] = A[M][K] @ B[N][K]^T ==========
// Generalized tile: waves in fixed 2x2; wave tile (BM/2)x(BN/2); acc[BM/32][BN/32].
// LDS chunk layout [4 ksegs][16 rows][8]; conflict-free ds_read_b128.
// Double-buffered LDS: stage(t+1) issued BEFORE compute(t).
// XCD-aware bijective block swizzle for L2 reuse.
// MODE: 0 plain fp32 C; 1 bias+relu; 2 C += acc + bias; 4 qkv-split bf16
// NOTE (r9 postmortem): one-shot 64KB-LDS variant and pinv thread-widening both
// REGRESSED (-200us total). This K-looped 16/32KB structure + 256t pinv_chain is
// the proven local optimum for the small shapes; do not re-attempt.
struct GP {
    const u16* A; const u16* B; float* C;
    u16* Q; u16* Kb; u16* V;
    const float* bias;
    long sA, sB, sC;
    int K, ldc, tilesN;
};

template <int BM, int BN, int MODE>
__global__ __launch_bounds__(256) void mgemm(GP p) {
    constexpr int FR = BM / 32;   // 16x16 fragments per wave (M)
    constexpr int FC = BN / 32;   // fragments per wave (N)
    constexpr int LA = BM / 64;   // A chunks staged per wave
    constexpr int LB = BN / 64;
    __shared__ u16 As[2 * BM * 32] __attribute__((aligned(16)));
    __shared__ u16 Bs[2 * BN * 32] __attribute__((aligned(16)));

    int tid = threadIdx.x, lane = tid & 63, wave = tid >> 6;
    int wm = wave >> 1, wn = wave & 1;
    // bijective XCD swizzle (T1, m204 variant)
    int nwg = gridDim.x, bid = blockIdx.x;
    int q = nwg >> 3, r = nwg & 7;
    int xcd = bid & 7, local = bid >> 3;
    int swz = (xcd < r ? xcd * (q + 1) : r * (q + 1) + (xcd - r) * q) + local;
    int tm = swz / p.tilesN, tn = swz % p.tilesN;
    int batch = blockIdx.y;
    int m0 = tm * BM, n0 = tn * BN;
    const u16* A = p.A + (long)batch * p.sA;
    const u16* B = p.B + (long)batch * p.sB;

    f32x4 acc[FR][FC];
#pragma unroll
    for (int i = 0; i < FR; i++)
#pragma unroll
        for (int j = 0; j < FC; j++) acc[i][j] = (f32x4){0.f, 0.f, 0.f, 0.f};

    int lr = lane & 15;
    int lcb = (lane >> 4) << 3;
    int quad = lane >> 4, cn = lane & 15;

    auto stage = [&](int buf, int k0) {
        u16* Ad = As + buf * (BM * 32);
        u16* Bd = Bs + buf * (BN * 32);
#pragma unroll
        for (int i = 0; i < LA; i++) {
            int chunk = wave * LA + i;
            gl_lds16(A + (long)(m0 + chunk * 16 + lr) * p.K + k0 + lcb,
                     Ad + chunk * 512 + lane * 8);
        }
#pragma unroll
        for (int i = 0; i < LB; i++) {
            int chunk = wave * LB + i;
            gl_lds16(B + (long)(n0 + chunk * 16 + lr) * p.K + k0 + lcb,
                     Bd + chunk * 512 + lane * 8);
        }
    };

    stage(0, 0);
    __syncthreads();  // vmcnt(0) drain + s_barrier: buf0 ready
    int cur = 0;
    for (int k0 = 0; k0 < p.K; k0 += 32) {
        if (k0 + 32 < p.K) stage(cur ^ 1, k0 + 32);  // async prefetch overlaps MFMA
        const u16* Asc = As + cur * (BM * 32);
        const u16* Bsc = Bs + cur * (BN * 32);
        bf16x8 af[FR], bfv[FC];
#pragma unroll
        for (int mi = 0; mi < FR; mi++)
            af[mi] = *(const bf16x8*)(Asc + (wm * FR + mi) * 512 + quad * 128 + cn * 8);
#pragma unroll
        for (int ni = 0; ni < FC; ni++)
            bfv[ni] = *(const bf16x8*)(Bsc + (wn * FC + ni) * 512 + quad * 128 + cn * 8);
#pragma unroll
        for (int mi = 0; mi < FR; mi++)
#pragma unroll
            for (int ni = 0; ni < FC; ni++)
                acc[mi][ni] = __builtin_amdgcn_mfma_f32_16x16x32_bf16(
                    af[mi], bfv[ni], acc[mi][ni], 0, 0, 0);
        __syncthreads();  // post-MFMA drain
        cur ^= 1;
    }

    if constexpr (MODE == 4) {
#pragma unroll
        for (int mi = 0; mi < FR; mi++) {
#pragma unroll
            for (int ni = 0; ni < FC; ni++) {
#pragma unroll
                for (int r = 0; r < 4; r++) {
                    int row = m0 + (wm * FR + mi) * 16 + quad * 4 + r;
                    int col = n0 + (wn * FC + ni) * 16 + cn;
                    float v = acc[mi][ni][r];
                    int h = col >> 6, d = col & 63;
                    if (col < 512)
                        p.Q[((long)h * 16384 + row) * 64 + d] = f2b(v * 0.125f);
                    else if (col < 1024)
                        p.Kb[((long)(h - 8) * 16384 + row) * 64 + d] = f2b(v);
                    else
                        p.V[((long)(h - 16) * 16384 + row) * 64 + d] = f2b(v);
                }
            }
        }
    } else {
        float* C = p.C + (long)batch * p.sC;
#pragma unroll
        for (int mi = 0; mi < FR; mi++) {
#pragma unroll
            for (int ni = 0; ni < FC; ni++) {
#pragma unroll
                for (int r = 0; r < 4; r++) {
                    int row = m0 + (wm * FR + mi) * 16 + quad * 4 + r;
                    int col = n0 + (wn * FC + ni) * 16 + cn;
                    float v = acc[mi][ni][r];
                    if (MODE == 0) {
                        C[(long)row * p.ldc + col] = v;
                    } else if (MODE == 1) {
                        C[(long)row * p.ldc + col] = fmaxf(v + p.bias[col], 0.f);
                    } else if (MODE == 2) {
                        C[(long)row * p.ldc + col] += v + p.bias[col];
                    }
                }
            }
        }
    }
}

template <int BM, int BN, int MODE>
static void launch_mgemm(hipStream_t st, GP p, int M, int N, int batch) {
    p.tilesN = N / BN;
    dim3 grid((M / BM) * (N / BN), batch);
    mgemm<BM, BN, MODE><<<grid, 256, 0, st>>>(p);
}

// ================= fused sim3 flash: O_partial = softmax-split(QL K^T) V ======
// 512 threads / 8 waves per block; each wave owns 32 QL rows. 2+ waves/SIMD.
__global__ __launch_bounds__(512) void flash_a3v(
    const u16* __restrict__ QLb, const u16* __restrict__ Kb,
    const u16* __restrict__ VT, float* __restrict__ PART) {
    __shared__ u16 QLs[16384] __attribute__((aligned(16)));  // 16rc x 2kc chunks
    __shared__ u16 Ks[4096] __attribute__((aligned(16)));    // 4rc x 2kc
    __shared__ u16 Vs[4096] __attribute__((aligned(16)));    // 4dc x 2kc
    __shared__ u16 Ps[16384] __attribute__((aligned(16)));   // per-wave 2mi x 2kc
    int tid = threadIdx.x, lane = tid & 63, w = tid >> 6;    // w in 0..7
    int head = blockIdx.y, split = blockIdx.x;
    const u16* QLh = QLb + (long)head * 256 * 64;
    const u16* Kh = Kb + ((long)head * 16384 + split * 512) * 64;
    const u16* Vh = VT + (long)head * 64 * 16384 + split * 512;
    int quad = lane >> 4, cn = lane & 15;
    int lr = lane & 15, lc = (lane >> 4) << 3;

    for (int c = w; c < 32; c += 8) {
        int rc = c >> 1, kc = c & 1;
        gl_lds16(QLh + (long)(rc * 16 + lr) * 64 + kc * 32 + lc, QLs + c * 512 + lane * 8);
    }
    __syncthreads();
    bf16x8 qf[2][2];
#pragma unroll
    for (int mi = 0; mi < 2; mi++)
#pragma unroll
        for (int kc = 0; kc < 2; kc++)
            qf[mi][kc] = *(const bf16x8*)(QLs + ((w * 2 + mi) * 2 + kc) * 512 +
                                          quad * 128 + cn * 8);

    f32x4 Oacc[2][4];
    float m_i[2][4], l_i[2][4];
#pragma unroll
    for (int i = 0; i < 2; i++)
#pragma unroll
        for (int j = 0; j < 4; j++) {
            Oacc[i][j] = (f32x4){0.f, 0.f, 0.f, 0.f};
            m_i[i][j] = -1e30f;
            l_i[i][j] = 0.f;
        }

    for (int t = 0; t < 8; t++) {
        {   // each of the 8 waves stages one K chunk and one V chunk
            int i = w;
            int rc = i >> 1, kc = i & 1;
            gl_lds16(Kh + (long)(t * 64 + rc * 16 + lr) * 64 + kc * 32 + lc,
                     Ks + i * 512 + lane * 8);
            gl_lds16(Vh + (long)(rc * 16 + lr) * 16384 + t * 64 + kc * 32 + lc,
                     Vs + i * 512 + lane * 8);
        }
        __syncthreads();
        f32x4 s[2][4];
#pragma unroll
        for (int i = 0; i < 2; i++)
#pragma unroll
            for (int j = 0; j < 4; j++) s[i][j] = (f32x4){0.f, 0.f, 0.f, 0.f};
#pragma unroll
        for (int kc = 0; kc < 2; kc++) {
            bf16x8 kf[4];
#pragma unroll
            for (int ni = 0; ni < 4; ni++)
                kf[ni] = *(const bf16x8*)(Ks + (ni * 2 + kc) * 512 + quad * 128 + cn * 8);
#pragma unroll
            for (int mi = 0; mi < 2; mi++)
#pragma unroll
                for (int ni = 0; ni < 4; ni++)
                    s[mi][ni] = __builtin_amdgcn_mfma_f32_16x16x32_bf16(
                        qf[mi][kc], kf[ni], s[mi][ni], 0, 0, 0);
        }
        // online softmax per row (mi, r); write P bf16 to this wave's Ps region
#pragma unroll
        for (int mi = 0; mi < 2; mi++) {
#pragma unroll
            for (int r = 0; r < 4; r++) {
                float mx = fmaxf(fmaxf(s[mi][0][r], s[mi][1][r]),
                                 fmaxf(s[mi][2][r], s[mi][3][r]));
                mx = fmaxf(mx, __shfl_xor(mx, 1));
                mx = fmaxf(mx, __shfl_xor(mx, 2));
                mx = fmaxf(mx, __shfl_xor(mx, 4));
                mx = fmaxf(mx, __shfl_xor(mx, 8));
                float mold = m_i[mi][r];
                float mnew = fmaxf(mold, mx);
                float alpha = __expf(mold - mnew);
                m_i[mi][r] = mnew;
                float sum = 0.f;
#pragma unroll
                for (int ni = 0; ni < 4; ni++) {
                    float e = __expf(s[mi][ni][r] - mnew);
                    sum += e;
                    int col = ni * 16 + cn;
                    Ps[w * 2048 + (mi * 2 + (col >> 5)) * 512 + ((col >> 3) & 3) * 128 +
                       (quad * 4 + r) * 8 + (col & 7)] = f2b(e);
                    Oacc[mi][ni][r] *= alpha;
                }
                sum += __shfl_xor(sum, 1);
                sum += __shfl_xor(sum, 2);
                sum += __shfl_xor(sum, 4);
                sum += __shfl_xor(sum, 8);
                l_i[mi][r] = l_i[mi][r] * alpha + sum;
            }
        }
        __syncthreads();
        // PV: O += P @ V
#pragma unroll
        for (int kc = 0; kc < 2; kc++) {
            bf16x8 vf[4], pf[2];
#pragma unroll
            for (int nd = 0; nd < 4; nd++)
                vf[nd] = *(const bf16x8*)(Vs + (nd * 2 + kc) * 512 + quad * 128 + cn * 8);
#pragma unroll
            for (int mi = 0; mi < 2; mi++)
                pf[mi] = *(const bf16x8*)(Ps + w * 2048 + (mi * 2 + kc) * 512 +
                                          quad * 128 + cn * 8);
#pragma unroll
            for (int mi = 0; mi < 2; mi++)
#pragma unroll
                for (int nd = 0; nd < 4; nd++)
                    Oacc[mi][nd] = __builtin_amdgcn_mfma_f32_16x16x32_bf16(
                        pf[mi], vf[nd], Oacc[mi][nd], 0, 0, 0);
        }
        __syncthreads();
    }
    float* base = PART + ((long)head * 32 + split) * 16896;
#pragma unroll
    for (int mi = 0; mi < 2; mi++) {
#pragma unroll
        for (int r = 0; r < 4; r++) {
            int row = w * 32 + mi * 16 + quad * 4 + r;
            if (cn == 0) {
                base[row] = m_i[mi][r];
                base[256 + row] = l_i[mi][r];
            }
#pragma unroll
            for (int ni = 0; ni < 4; ni++)
                base[512 + row * 64 + ni * 16 + cn] = Oacc[mi][ni][r];
        }
    }
}

// combine partials: O[h][row][d] = sum_b exp(m_b-m) O_b / sum_b exp(m_b-m) l_b
__global__ __launch_bounds__(256) void a3v_combine(const float* __restrict__ PART,
                                                   float* __restrict__ O) {
    int head = blockIdx.x, rg = blockIdx.y;
    int t = threadIdx.x;
    int rl = t >> 6, d = t & 63;
    int row = rg * 4 + rl;
    const float* ph = PART + (long)head * 32 * 16896;
    float m = -1e30f;
#pragma unroll 8
    for (int b = 0; b < 32; b++) m = fmaxf(m, ph[b * 16896 + row]);
    float l = 0.f, o = 0.f;
#pragma unroll 8
    for (int b = 0; b < 32; b++) {
        float a = __expf(ph[b * 16896 + row] - m);
        l += a * ph[b * 16896 + 256 + row];
        o += a * ph[b * 16896 + 512 + row * 64 + d];
    }
    O[((long)head * 256 + row) * 64 + d] = o / l;
}

// ================= fused sim1 -> softmax -> @W2 -> +conv -> bf16 ==============
// Round 10: depthwise conv residual fused in (conv_kernel deleted). Same block
// decomposition as the old conv kernel, same k-order fp32 accumulation over the
// same b2f(VT) values -> bit-identical output; saves the 32MB LNA write + 32MB
// read + VT re-read + one launch per layer. LDS 64->76.5KB keeps 2 blocks/CU.
__global__ __launch_bounds__(256) void attn1_fused(
    const u16* __restrict__ Qb, const u16* __restrict__ KLb,
    const u16* __restrict__ W2T, const u16* __restrict__ VT,
    const float* __restrict__ cw, u16* __restrict__ OUTb) {
    __shared__ u16 lds[32768] __attribute__((aligned(16)));
    __shared__ u16 vtb[64 * 96] __attribute__((aligned(16)));   // conv window (bf16)
    __shared__ float sw[33];
    u16* Qs = lds;
    u16* KLs = lds + 4096;
    u16* Ps = lds;
    u16* W2s = lds + 16384;
    int tid = threadIdx.x, lane = tid & 63, w = tid >> 6;
    int head = blockIdx.y, n0 = blockIdx.x * 64;
    int quad = lane >> 4, cn = lane & 15;
    int lr = lane & 15, lc = (lane >> 4) << 3;
    const u16* Qh = Qb + (long)head * 16384 * 64;
    const u16* KLh = KLb + (long)head * 256 * 64;
    const u16* W2h = W2T + (long)head * 64 * 256;
    // stage conv inputs: vtb[d][j] = VT[h][d][n0-16+j] (zero-padded), sw = weights
    for (int i = tid; i < 64 * 96; i += 256) {
        int d = i / 96, j = i % 96;
        int n = n0 - 16 + j;
        u16 v = 0;
        if (n >= 0 && n < 16384) v = VT[((long)head * 64 + d) * 16384 + n];
        vtb[i] = v;
    }
    if (tid < 33) sw[tid] = cw[head * 33 + tid];
#pragma unroll
    for (int c = 0; c < 2; c++)
        gl_lds16(Qh + (long)(n0 + w * 16 + lr) * 64 + c * 32 + lc,
                 Qs + c * 2048 + w * 512 + lane * 8);
#pragma unroll
    for (int c = 0; c < 2; c++)
#pragma unroll
        for (int rg = 0; rg < 4; rg++) {
            int chunk = rg * 4 + w;
            gl_lds16(KLh + (long)(chunk * 16 + lr) * 64 + c * 32 + lc,
                     KLs + c * 8192 + chunk * 512 + lane * 8);
        }
    __syncthreads();
    f32x4 acc[16];
#pragma unroll
    for (int i = 0; i < 16; i++) acc[i] = (f32x4){0.f, 0.f, 0.f, 0.f};
#pragma unroll
    for (int c = 0; c < 2; c++) {
        bf16x8 af = *(const bf16x8*)(Qs + c * 2048 + w * 512 + quad * 128 + cn * 8);
#pragma unroll
        for (int ni = 0; ni < 16; ni++) {
            bf16x8 bfv = *(const bf16x8*)(KLs + c * 8192 + ni * 512 + quad * 128 + cn * 8);
            acc[ni] = __builtin_amdgcn_mfma_f32_16x16x32_bf16(af, bfv, acc[ni], 0, 0, 0);
        }
    }
    __syncthreads();
#pragma unroll
    for (int r = 0; r < 4; r++) {
        float mx = -1e30f;
#pragma unroll
        for (int ni = 0; ni < 16; ni++) mx = fmaxf(mx, acc[ni][r]);
        mx = fmaxf(mx, __shfl_xor(mx, 1));
        mx = fmaxf(mx, __shfl_xor(mx, 2));
        mx = fmaxf(mx, __shfl_xor(mx, 4));
        mx = fmaxf(mx, __shfl_xor(mx, 8));
        float e[16];
        float s = 0.f;
#pragma unroll
        for (int ni = 0; ni < 16; ni++) {
            e[ni] = __expf(acc[ni][r] - mx);
            s += e[ni];
        }
        s += __shfl_xor(s, 1);
        s += __shfl_xor(s, 2);
        s += __shfl_xor(s, 4);
        s += __shfl_xor(s, 8);
        float inv = 1.f / s;
        int prow = w * 16 + quad * 4 + r;
#pragma unroll
        for (int ni = 0; ni < 16; ni++) {
            int k = ni * 16 + cn;
            Ps[(k >> 5) * 2048 + ((k >> 3) & 3) * 512 + prow * 8 + (k & 7)] =
                f2b(e[ni] * inv);
        }
    }
#pragma unroll
    for (int c = 0; c < 8; c++)
        gl_lds16(W2h + (long)(w * 16 + lr) * 256 + c * 32 + lc,
                 W2s + c * 2048 + w * 512 + lane * 8);
    __syncthreads();
    f32x4 acc2[4];
#pragma unroll
    for (int i = 0; i < 4; i++) acc2[i] = (f32x4){0.f, 0.f, 0.f, 0.f};
#pragma unroll
    for (int c = 0; c < 8; c++) {
        bf16x8 af = *(const bf16x8*)(Ps + c * 2048 + quad * 512 + (w * 16 + cn) * 8);
#pragma unroll
        for (int ni = 0; ni < 4; ni++) {
            bf16x8 bfv = *(const bf16x8*)(W2s + c * 2048 + ni * 512 + quad * 128 + cn * 8);
            acc2[ni] = __builtin_amdgcn_mfma_f32_16x16x32_bf16(af, bfv, acc2[ni], 0, 0, 0);
        }
    }
#pragma unroll
    for (int ni = 0; ni < 4; ni++)
#pragma unroll
        for (int r = 0; r < 4; r++) {
            int row = n0 + w * 16 + quad * 4 + r;
            int dl = ni * 16 + cn;
            int jb = w * 16 + quad * 4 + r;  // row - n0
            float cv = 0.f;
#pragma unroll
            for (int k = 0; k < 33; k++) cv += sw[k] * b2f(vtb[dl * 96 + jb + k]);
            long idx = (long)row * 512 + head * 64 + dl;
            OUTb[idx] = f2b(cv + acc2[ni][r]);
        }
}

// ================= fp32 tile GEMM (W2T = (z @ a3v) transposed bf16) ============
// Round 10: f2b + transposed store fused in (w2t_kernel deleted; fp32 W2 buffer
// dead). Same acc value through f2b -> bit-identical.
#define TILE 64
#define KT 16
#define LDP (TILE + 4)
__global__ __launch_bounds__(256) void gemm32t_kernel(
    const float* __restrict__ A, const float* __restrict__ B, u16* __restrict__ CT,
    int M, int N, int K, int lda, int ldb,
    long sA, long sB, int tilesN) {
    int tm = blockIdx.x / tilesN, tn = blockIdx.x % tilesN;
    int batch = blockIdx.y;
    A += (long)batch * sA; B += (long)batch * sB;
    int row0 = tm * TILE, col0 = tn * TILE;
    __shared__ float As[KT][LDP];
    __shared__ float Bs[KT][LDP];
    int t = threadIdx.x;
    int tx = t & 15, ty = t >> 4;
    float acc[4][4] = {{0.f}};
    int aRow = t >> 2, aK = (t & 3) << 2;
    int bN = t & 63, bK = (t >> 6) << 2;
    for (int k0 = 0; k0 < K; k0 += KT) {
        {
            int r = row0 + aRow;
            float4 av = make_float4(0.f, 0.f, 0.f, 0.f);
            if (r < M) av = *(const float4*)(A + (long)r * lda + k0 + aK);
            As[aK][aRow] = av.x; As[aK + 1][aRow] = av.y;
            As[aK + 2][aRow] = av.z; As[aK + 3][aRow] = av.w;
        }
        {
            const float* bp = B + (long)(k0 + bK) * ldb + col0 + bN;
            bool ok = col0 + bN < N;
#pragma unroll
            for (int j = 0; j < 4; j++) Bs[bK + j][bN] = ok ? bp[(long)j * ldb] : 0.f;
        }
        __syncthreads();
#pragma unroll
        for (int kk = 0; kk < KT; kk++) {
            float4 a = *(const float4*)&As[kk][ty << 2];
            float4 b = *(const float4*)&Bs[kk][tx << 2];
            acc[0][0] += a.x * b.x; acc[0][1] += a.x * b.y; acc[0][2] += a.x * b.z; acc[0][3] += a.x * b.w;
            acc[1][0] += a.y * b.x; acc[1][1] += a.y * b.y; acc[1][2] += a.y * b.z; acc[1][3] += a.y * b.w;
            acc[2][0] += a.z * b.x; acc[2][1] += a.z * b.y; acc[2][2] += a.z * b.z; acc[2][3] += a.z * b.w;
            acc[3][0] += a.w * b.x; acc[3][1] += a.w * b.y; acc[3][2] += a.w * b.z; acc[3][3] += a.w * b.w;
        }
        __syncthreads();
    }
    // CT[batch][col][row] = f2b(acc)  (stride: batch M*N, col M)
#pragma unroll
    for (int i = 0; i < 4; i++) {
        int row = row0 + (ty << 2) + i;
        if (row >= M) continue;
#pragma unroll
        for (int j = 0; j < 4; j++) {
            int col = col0 + (tx << 2) + j;
            if (col >= N) continue;
            CT[(long)batch * M * N + (long)col * M + row] = f2b(acc[i][j]);
        }
    }
}
static void gemm32t(hipStream_t st, int M, int N, int K,
                    const float* A, int lda, long sA,
                    const float* B, int ldb, long sB,
                    u16* CT, int batch) {
    int tilesM = (M + TILE - 1) / TILE, tilesN = (N + TILE - 1) / TILE;
    dim3 grid(tilesM * tilesN, batch);
    gemm32t_kernel<<<grid, 256, 0, st>>>(A, B, CT, M, N, K, lda, ldb, sA, sB, tilesN);
}

// ================= pinv fused chain (fp32; also emits z^T bf16) ================
// Register version (round-2 proven): per-thread row reads are L2-resident with
// high TLP. LDS-tiling (-13us/launch) and 512t widening (2x read traffic) both
// measured as regressions; keep this form.
__global__ __launch_bounds__(256) void pinv_chain(const float* __restrict__ xz,
                                                  const float* __restrict__ z,
                                                  float* __restrict__ zn,
                                                  u16* __restrict__ znT) {
    int h = blockIdx.y, c0 = blockIdx.x * 8;
    const float* X = xz + (long)h * 65536;
    const float* Z = z + (long)h * 65536;
    __shared__ float ta[256][8];
    __shared__ float tb[256][8];
    int t = threadIdx.x;
    const float4* X4 = (const float4*)(X + t * 256);
    const float4* Z4 = (const float4*)(Z + t * 256);
    float acc[8];
#pragma unroll
    for (int j = 0; j < 8; j++)
        ta[t][j] = ((t == c0 + j) ? 7.f : 0.f) - X[t * 256 + c0 + j];
    __syncthreads();
#pragma unroll
    for (int j = 0; j < 8; j++) acc[j] = 0.f;
    for (int k4 = 0; k4 < 64; k4++) {
        float4 xv = X4[k4];
#pragma unroll
        for (int j = 0; j < 8; j++)
            acc[j] += xv.x * ta[k4 * 4][j] + xv.y * ta[k4 * 4 + 1][j] +
                      xv.z * ta[k4 * 4 + 2][j] + xv.w * ta[k4 * 4 + 3][j];
    }
#pragma unroll
    for (int j = 0; j < 8; j++)
        tb[t][j] = ((t == c0 + j) ? 15.f : 0.f) - acc[j];
    __syncthreads();
#pragma unroll
    for (int j = 0; j < 8; j++) acc[j] = 0.f;
    for (int k4 = 0; k4 < 64; k4++) {
        float4 xv = X4[k4];
#pragma unroll
        for (int j = 0; j < 8; j++)
            acc[j] += xv.x * tb[k4 * 4][j] + xv.y * tb[k4 * 4 + 1][j] +
                      xv.z * tb[k4 * 4 + 2][j] + xv.w * tb[k4 * 4 + 3][j];
    }
    __syncthreads();
#pragma unroll
    for (int j = 0; j < 8; j++)
        ta[t][j] = ((t == c0 + j) ? 13.f : 0.f) - acc[j];
    __syncthreads();
#pragma unroll
    for (int j = 0; j < 8; j++) acc[j] = 0.f;
    for (int k4 = 0; k4 < 64; k4++) {
        float4 zv = Z4[k4];
#pragma unroll
        for (int j = 0; j < 8; j++)
            acc[j] += zv.x * ta[k4 * 4][j] + zv.y * ta[k4 * 4 + 1][j] +
                      zv.z * ta[k4 * 4 + 2][j] + zv.w * ta[k4 * 4 + 3][j];
    }
#pragma unroll
    for (int j = 0; j < 8; j++) {
        float v = 0.25f * acc[j];
        zn[(long)h * 65536 + t * 256 + c0 + j] = v;
        znT[(long)h * 65536 + (c0 + j) * 256 + t] = f2b(v);
    }
}

// ================= layernorm / softmax / misc =================================
__global__ __launch_bounds__(256) void layernorm_bf16(
    const float* __restrict__ x, const float* __restrict__ g,
    const float* __restrict__ b, u16* __restrict__ y) {
    __shared__ float sm[4];
    long base = (long)blockIdx.x * 512;
    int t = threadIdx.x;
    float v0 = x[base + t], v1 = x[base + 256 + t];
    float s = wred_sum(v0 + v1);
    if ((t & 63) == 0) sm[t >> 6] = s;
    __syncthreads();
    float mu = (sm[0] + sm[1] + sm[2] + sm[3]) * (1.f / 512.f);
    __syncthreads();
    float d0 = v0 - mu, d1 = v1 - mu;
    float q = wred_sum(d0 * d0 + d1 * d1);
    if ((t & 63) == 0) sm[t >> 6] = q;
    __syncthreads();
    float var = (sm[0] + sm[1] + sm[2] + sm[3]) * (1.f / 512.f);
    float rstd = rsqrtf(var + 1e-5f);
    y[base + t] = f2b(d0 * rstd * g[t] + b[t]);
    y[base + 256 + t] = f2b(d1 * rstd * g[256 + t] + b[256 + t]);
}

// softmax fp32 in place (ncols=256); bf16 copy; fused |col|-sum accumulation.
// a2 is post-softmax (positive, row-sum==1) so reference's max(col)==1 exactly;
// only the column sums are needed for the pinv scale.
__global__ __launch_bounds__(256) void softmax_rows_cs(float* __restrict__ data,
                                                       u16* __restrict__ outb,
                                                       float* __restrict__ colsum) {
    __shared__ float sm[4];
    float* row = data + (long)blockIdx.x * 256;
    u16* rowb = outb + (long)blockIdx.x * 256;
    int h = blockIdx.x >> 8;
    int t = threadIdx.x;
    float v0 = row[t];
    float m = wred_max(v0);
    if ((t & 63) == 0) sm[t >> 6] = m;
    __syncthreads();
    m = fmaxf(fmaxf(sm[0], sm[1]), fmaxf(sm[2], sm[3]));
    __syncthreads();
    float e = __expf(v0 - m);
    float s = wred_sum(e);
    if ((t & 63) == 0) sm[t >> 6] = s;
    __syncthreads();
    s = sm[0] + sm[1] + sm[2] + sm[3];
    float v = e / s;
    row[t] = v;
    rowb[t] = f2b(v);
    atomicAdd(&colsum[h * 256 + t], v);
}

__global__ void cls_copy(const float* __restrict__ cls, float* __restrict__ X) {
    X[threadIdx.x] = cls[threadIdx.x];
}
__global__ void build_hb(const float* __restrict__ h, u16* __restrict__ dst) {
    long idx = (long)blockIdx.x * 256 + threadIdx.x;
    long row = idx >> 10;
    int col = (int)(idx & 1023);
    float v = (row == 0) ? 0.f : h[((row - 1) << 10) + col];
    dst[idx] = f2b(v);
}
// LDS-tiled fp32 -> bf16 transpose: coalesced loads and coalesced stores.
__global__ __launch_bounds__(256) void transpose_to_bf16_t(
    const float* __restrict__ src, u16* __restrict__ dst, int R, int C) {
    __shared__ u16 tile[64][65];
    int tilesC = C >> 6;
    int rt = blockIdx.x / tilesC, ct = blockIdx.x % tilesC;
    int t = threadIdx.x, w = t >> 6, lane = t & 63;
    const float* sp = src + (long)(rt * 64) * C + ct * 64;
#pragma unroll
    for (int k = 0; k < 16; k++) {
        int r = w * 16 + k;
        tile[lane][r] = f2b(sp[(long)r * C + lane]);
    }
    __syncthreads();
    u16* dp = dst + (long)(ct * 64) * R + rt * 64;
#pragma unroll
    for (int k = 0; k < 16; k++) {
        int c = w * 16 + k;
        dp[(long)c * R + lane] = tile[c][lane];
    }
}
__global__ __launch_bounds__(256) void transpose_v(const u16* __restrict__ Vb,
                                                   u16* __restrict__ VT) {
    __shared__ u16 tile[64][68];
    int h = blockIdx.y, n0 = blockIdx.x * 64;
    int t = threadIdx.x;
    int i = t >> 2, seg = t & 3;
    const u16* src = Vb + ((long)h * 16384 + n0 + i) * 64 + seg * 16;
#pragma unroll
    for (int j = 0; j < 16; j++) tile[seg * 16 + j][i] = src[j];
    __syncthreads();
    u16* dst = VT + ((long)h * 64 + i) * 16384 + n0 + seg * 16;
#pragma unroll
    for (int j = 0; j < 16; j++) dst[j] = tile[i][seg * 16 + j];
}
__global__ void landmarks_b(const u16* __restrict__ Qb, const u16* __restrict__ Kb,
                            u16* __restrict__ QLb, u16* __restrict__ KLb) {
    int h = blockIdx.x >> 8, j = blockIdx.x & 255, d = threadIdx.x;
    const u16* qb = Qb + ((long)h * 16384 + j * 64) * 64 + d;
    const u16* kb = Kb + ((long)h * 16384 + j * 64) * 64 + d;
    float sq = 0.f, sk = 0.f;
    for (int tk = 0; tk < 64; ++tk) {
        sq += b2f(qb[tk * 64]);
        sk += b2f(kb[tk * 64]);
    }
    QLb[((h << 8) + j) * 64 + d] = f2b(sq * (1.f / 64.f));
    KLb[((h << 8) + j) * 64 + d] = f2b(sk * (1.f / 64.f));
}

// finalize pinv scale: maxes[0]=1 (softmax row-sums), maxes[1]=max column sum.
__global__ __launch_bounds__(256) void pinv_absmax_fin(const float* __restrict__ colsum,
                                                       float* __restrict__ maxes) {
    __shared__ float sm[4];
    int t = threadIdx.x;
    float m = 0.f;
#pragma unroll
    for (int h = 0; h < 8; h++) m = fmaxf(m, colsum[h * 256 + t]);
    m = wred_max(m);
    if ((t & 63) == 0) sm[t >> 6] = m;
    __syncthreads();
    if (t == 0) {
        maxes[0] = 1.0f;
        maxes[1] = fmaxf(fmaxf(sm[0], sm[1]), fmaxf(sm[2], sm[3]));
    }
}

// z0 = a2^T * s (fp32) and z0^T bf16 (= a2 * s)
__global__ void pinv_init(const float* __restrict__ a2, const float* __restrict__ maxes,
                          float* __restrict__ z, u16* __restrict__ zT) {
    long idx = (long)blockIdx.x * 256 + threadIdx.x;
    int h = (int)(idx >> 16);
    int rem = (int)(idx & 65535);
    int i = rem >> 8, j = rem & 255;
    float inv = 1.f / (maxes[0] * maxes[1]);
    float v = a2[((long)h << 16) + (j << 8) + i] * inv;
    z[idx] = v;
    zT[((long)h << 16) + (j << 8) + i] = f2b(v);
}
__global__ __launch_bounds__(256) void final_head(
    const float* __restrict__ X, const float* __restrict__ g, const float* __restrict__ b,
    const float* __restrict__ W, const float* __restrict__ bias, float* __restrict__ out) {
    __shared__ float sm[4];
    __shared__ float ln0[512];
    int t = threadIdx.x;
    float v0 = X[t], v1 = X[256 + t];
    float s = wred_sum(v0 + v1);
    if ((t & 63) == 0) sm[t >> 6] = s;
    __syncthreads();
    float mu = (sm[0] + sm[1] + sm[2] + sm[3]) * (1.f / 512.f);
    __syncthreads();
    float d0 = v0 - mu, d1 = v1 - mu;
    float q = wred_sum(d0 * d0 + d1 * d1);
    if ((t & 63) == 0) sm[t >> 6] = q;
    __syncthreads();
    float rstd = rsqrtf((sm[0] + sm[1] + sm[2] + sm[3]) * (1.f / 512.f) + 1e-5f);
    ln0[t] = d0 * rstd * g[t] + b[t];
    ln0[256 + t] = d1 * rstd * g[256 + t] + b[256 + t];
    __syncthreads();
    int jj = blockIdx.x * 256 + t;
    if (jj < 1000) {
        float acc = bias[jj];
        for (int dd = 0; dd < 512; ++dd) acc += ln0[dd] * W[dd * 1000 + jj];
        out[jj] = acc;
    }
}

// ================= layer driver ================================================
struct Bufs {
    float *X, *A2, *Z0, *Z1, *XZ, *O, *MAXES, *COLSUM, *PART;
    u16 *LNb, *Qb, *Kb, *Vb, *VT, *QLb, *KLb, *W2T, *W1T, *QKVWT, *OUTWT;
    u16 *A2b, *ZT0, *ZT1;
};

static void run_layer(hipStream_t st, Bufs& B,
                      const float* ln_g, const float* ln_b, const float* qkv_W,
                      const float* conv_W, const float* out_W, const float* out_b) {
    const int N = 16384, D = 512, H = 8, DH = 64, M = 256;
    GP p{};
    // 1. LN -> bf16
    layernorm_bf16<<<N, 256, 0, st>>>(B.X, ln_g, ln_b, B.LNb);
    // 2. qkv (row-major q/k/v epilogue), then VT transpose
    transpose_to_bf16_t<<<(512 / 64) * (1536 / 64), 256, 0, st>>>(qkv_W, B.QKVWT, 512, 1536);
    p = GP{}; p.A = B.LNb; p.B = B.QKVWT; p.Q = B.Qb; p.Kb = B.Kb; p.V = B.Vb; p.K = 512;
    launch_mgemm<128, 128, 4>(st, p, N, 1536, 1);
    transpose_v<<<dim3(256, 8), 256, 0, st>>>(B.Vb, B.VT);
    // 3. landmarks
    landmarks_b<<<H * M, 64, 0, st>>>(B.Qb, B.Kb, B.QLb, B.KLb);
    // 4. sim2 -> softmax (fp32 + bf16 + colsum) -> pinv
    p = GP{}; p.A = B.QLb; p.B = B.KLb; p.C = B.A2; p.K = DH; p.ldc = M;
    p.sA = (long)M * DH; p.sB = (long)M * DH; p.sC = (long)M * M;
    launch_mgemm<64, 64, 0>(st, p, M, M, H);
    hipMemsetAsync(B.COLSUM, 0, 8 * 256 * 4, st);
    softmax_rows_cs<<<H * M, 256, 0, st>>>(B.A2, B.A2b, B.COLSUM);
    pinv_absmax_fin<<<1, 256, 0, st>>>(B.COLSUM, B.MAXES);
    pinv_init<<<(H * M * M) / 256, 256, 0, st>>>(B.A2, B.MAXES, B.Z0, B.ZT0);
    float* z = B.Z0; float* zn = B.Z1;
    u16* zt = B.ZT0; u16* ztn = B.ZT1;
    for (int it = 0; it < 6; ++it) {
        // XZ = a2 @ z via bf16 MFMA (NT with z^T); 64-tile -> 128 blocks
        p = GP{}; p.A = B.A2b; p.B = zt; p.C = B.XZ; p.K = M; p.ldc = M;
        p.sA = (long)M * M; p.sB = (long)M * M; p.sC = (long)M * M;
        launch_mgemm<64, 64, 0>(st, p, M, M, H);
        pinv_chain<<<dim3(32, 8), 256, 0, st>>>(B.XZ, z, zn, ztn);
        float* t1 = z; z = zn; zn = t1;
        u16* t2 = zt; zt = ztn; ztn = t2;
    }
    // 5. fused sim3 flash (split over 32 key-ranges; 512 thr / 8 waves) + combine
    flash_a3v<<<dim3(32, 8), 512, 0, st>>>(B.QLb, B.Kb, B.VT, B.PART);
    a3v_combine<<<dim3(8, 64), 256, 0, st>>>(B.PART, B.O);
    // 6. W2T = (z @ a3v)^T bf16 directly (w2t fused)
    gemm32t(st, M, DH, M, z, M, (long)M * M, B.O, DH, (long)M * DH, B.W2T, H);
    // 7. fused sim1 -> softmax -> @W2 -> +conv(in-kernel) -> LNb (bf16)
    attn1_fused<<<dim3(N / 64, H), 256, 0, st>>>(B.Qb, B.KLb, B.W2T, B.VT, conv_W, B.LNb);
    // 8. out projection: X += ATTN @ out_W + out_b
    transpose_to_bf16_t<<<(512 / 64) * (512 / 64), 256, 0, st>>>(out_W, B.OUTWT, 512, 512);
    p = GP{}; p.A = B.LNb; p.B = B.OUTWT; p.C = B.X; p.bias = out_b; p.K = D; p.ldc = D;
    launch_mgemm<128, 128, 2>(st, p, N, D, 1);
}

extern "C" void kernel_launch(void* const* d_in, const int* in_sizes, int n_in,
                              void* d_out, int out_size, void* d_ws, size_t ws_size,
                              hipStream_t stream) {
    const float* h_in = (const float*)d_in[0];
    const float* W1 = (const float*)d_in[1];
    const float* b1 = (const float*)d_in[2];
    const float* cls = (const float*)d_in[3];
    const float* ln1_g = (const float*)d_in[4];
    const float* ln1_b = (const float*)d_in[5];
    const float* qkv1_W = (const float*)d_in[6];
    const float* conv1_W = (const float*)d_in[7];
    const float* out1_W = (const float*)d_in[8];
    const float* out1_b = (const float*)d_in[9];
    const float* ln2_g = (const float*)d_in[10];
    const float* ln2_b = (const float*)d_in[11];
    const float* qkv2_W = (const float*)d_in[12];
    const float* conv2_W = (const float*)d_in[13];
    const float* out2_W = (const float*)d_in[14];
    const float* out2_b = (const float*)d_in[15];
    const float* lnf_g = (const float*)d_in[16];
    const float* lnf_b = (const float*)d_in[17];
    const float* fc2_W = (const float*)d_in[18];
    const float* fc2_b = (const float*)d_in[19];
    float* out = (float*)d_out;

    char* wsb = (char*)d_ws;
    size_t off = 0;
    auto alloc = [&](size_t bytes) -> void* {
        void* p = (void*)(wsb + off);
        off += (bytes + 255) & ~(size_t)255;
        return p;
    };
    Bufs B;
    B.X    = (float*)alloc((size_t)16384 * 512 * 4);
    B.LNb  = (u16*)alloc((size_t)16384 * 512 * 2);
    B.Qb   = (u16*)alloc((size_t)8 * 16384 * 64 * 2);   // adjacent to Kb: HB alias
    B.Kb   = (u16*)alloc((size_t)8 * 16384 * 64 * 2);
    B.VT   = (u16*)alloc((size_t)8 * 64 * 16384 * 2);
    B.QLb  = (u16*)alloc((size_t)8 * 256 * 64 * 2);
    B.KLb  = (u16*)alloc((size_t)8 * 256 * 64 * 2);
    B.A2   = (float*)alloc((size_t)8 * 256 * 256 * 4);
    B.A2b  = (u16*)alloc((size_t)8 * 256 * 256 * 2);
    B.Z0   = (float*)alloc((size_t)8 * 256 * 256 * 4);
    B.Z1   = (float*)alloc((size_t)8 * 256 * 256 * 4);
    B.ZT0  = (u16*)alloc((size_t)8 * 256 * 256 * 2);
    B.ZT1  = (u16*)alloc((size_t)8 * 256 * 256 * 2);
    B.XZ   = (float*)alloc((size_t)8 * 256 * 256 * 4);
    B.O    = (float*)alloc((size_t)8 * 256 * 64 * 4);
    B.W2T  = (u16*)alloc((size_t)8 * 64 * 256 * 2);
    B.W1T  = (u16*)alloc((size_t)512 * 1024 * 2);
    B.QKVWT = (u16*)alloc((size_t)1536 * 512 * 2);
    B.OUTWT = (u16*)alloc((size_t)512 * 512 * 2);
    B.MAXES = (float*)alloc(256);
    B.COLSUM = (float*)alloc((size_t)8 * 256 * 4);
    // union region: Vb (16 MB, dead after transpose_v) aliases PART (17.3 MB)
    {
        size_t vb = (size_t)8 * 16384 * 64 * 2;
        size_t part = (size_t)8 * 32 * 16896 * 4;
        void* region = alloc(part > vb ? part : vb);
        B.Vb = (u16*)region;
        B.PART = (float*)region;
    }
    if (off > ws_size) return;  // fail loudly (output stays poisoned)

    // fc1: HB (aliases Qb..Kb, 32MB) = [0; h] bf16; X = relu(HB @ W1^T + b1); X[0]=cls
    u16* HB = B.Qb;
    build_hb<<<(16384 * 1024) / 256, 256, 0, stream>>>(h_in, HB);
    transpose_to_bf16_t<<<(1024 / 64) * (512 / 64), 256, 0, stream>>>(W1, B.W1T, 1024, 512);
    {
        GP p{}; p.A = HB; p.B = B.W1T; p.C = B.X; p.bias = b1; p.K = 1024; p.ldc = 512;
        launch_mgemm<128, 128, 1>(stream, p, 16384, 512, 1);
    }
    cls_copy<<<1, 512, 0, stream>>>(cls, B.X);

    run_layer(stream, B, ln1_g, ln1_b, qkv1_W, conv1_W, out1_W, out1_b);
    run_layer(stream, B, ln2_g, ln2_b, qkv2_W, conv2_W, out2_W, out2_b);

    final_head<<<4, 256, 0, stream>>>(B.X, lnf_g, lnf_b, fc2_W, fc2_b, out);
}

// Round 12
// 1276.063 us; speedup vs baseline: 1.1844x; 1.1844x over previous
//
#include <hip/hip_runtime.h>
#include <math.h>

typedef unsigned short u16;
typedef short bf16x8 __attribute__((ext_vector_type(8)));
typedef float f32x4 __attribute__((ext_vector_type(4)));

__device__ __forceinline__ u16 f2b(float x) {
    unsigned u = __builtin_bit_cast(unsigned, x);
    unsigned r = u + 0x7fffu + ((u >> 16) & 1u);
    return (u16)(r >> 16);
}
__device__ __forceinline__ float b2f(u16 v) {
    return __builtin_bit_cast(float, (unsigned)v << 16);
}
__device__ __forceinline__ void gl_lds16(const u16* g, u16* l) {
    __builtin_amdgcn_global_load_lds(
        (const __attribute__((address_space(1))) unsigned int*)g,
        (__attribute__((address_space(3))) unsigned int*)l, 16, 0, 0);
}
__device__ __forceinline__ float wred_sum(float v) {
#pragma unroll
    for (int o = 32; o > 0; o >>= 1) v += __shfl_down(v, o, 64);
    return v;
}
__device__ __forceinline__ float wred_max(float v) {
#pragma unroll
    for (int o = 32; o > 0; o >>= 1) v = fmaxf(v, __shfl_down(v, o, 64));
    return v;
}

// ================= bf16 MFMA GEMM (NT): C[M][N] = A[M][K] @ B[N][K]^T ==========
// Generalized tile: waves in fixed 2x2; wave tile (BM/2)x(BN/2); acc[BM/32][BN/32].
// LDS chunk layout [4 ksegs][16 rows][8]; conflict-free ds_read_b128.
// Double-buffered LDS: stage(t+1) issued BEFORE compute(t).
// XCD-aware bijective block swizzle for L2 reuse.
// MODE: 0 plain fp32 C; 1 bias+relu; 2 C += acc + bias; 4 qkv-split bf16
// NOTE (r9/r11 postmortems): one-shot 64KB-LDS gemm, pinv thread-widening, and
// in-epilogue conv fusion (u16 stride-96 LDS = 8-way bank conflict, 5.3e7 hits)
// ALL regressed. Keep this structure; conv stays a separate kernel.
struct GP {
    const u16* A; const u16* B; float* C;
    u16* Q; u16* Kb; u16* V;
    const float* bias;
    long sA, sB, sC;
    int K, ldc, tilesN;
};

template <int BM, int BN, int MODE>
__global__ __launch_bounds__(256) void mgemm(GP p) {
    constexpr int FR = BM / 32;   // 16x16 fragments per wave (M)
    constexpr int FC = BN / 32;   // fragments per wave (N)
    constexpr int LA = BM / 64;   // A chunks staged per wave
    constexpr int LB = BN / 64;
    __shared__ u16 As[2 * BM * 32] __attribute__((aligned(16)));
    __shared__ u16 Bs[2 * BN * 32] __attribute__((aligned(16)));

    int tid = threadIdx.x, lane = tid & 63, wave = tid >> 6;
    int wm = wave >> 1, wn = wave & 1;
    // bijective XCD swizzle (T1, m204 variant)
    int nwg = gridDim.x, bid = blockIdx.x;
    int q = nwg >> 3, r = nwg & 7;
    int xcd = bid & 7, local = bid >> 3;
    int swz = (xcd < r ? xcd * (q + 1) : r * (q + 1) + (xcd - r) * q) + local;
    int tm = swz / p.tilesN, tn = swz % p.tilesN;
    int batch = blockIdx.y;
    int m0 = tm * BM, n0 = tn * BN;
    const u16* A = p.A + (long)batch * p.sA;
    const u16* B = p.B + (long)batch * p.sB;

    f32x4 acc[FR][FC];
#pragma unroll
    for (int i = 0; i < FR; i++)
#pragma unroll
        for (int j = 0; j < FC; j++) acc[i][j] = (f32x4){0.f, 0.f, 0.f, 0.f};

    int lr = lane & 15;
    int lcb = (lane >> 4) << 3;
    int quad = lane >> 4, cn = lane & 15;

    auto stage = [&](int buf, int k0) {
        u16* Ad = As + buf * (BM * 32);
        u16* Bd = Bs + buf * (BN * 32);
#pragma unroll
        for (int i = 0; i < LA; i++) {
            int chunk = wave * LA + i;
            gl_lds16(A + (long)(m0 + chunk * 16 + lr) * p.K + k0 + lcb,
                     Ad + chunk * 512 + lane * 8);
        }
#pragma unroll
        for (int i = 0; i < LB; i++) {
            int chunk = wave * LB + i;
            gl_lds16(B + (long)(n0 + chunk * 16 + lr) * p.K + k0 + lcb,
                     Bd + chunk * 512 + lane * 8);
        }
    };

    stage(0, 0);
    __syncthreads();  // vmcnt(0) drain + s_barrier: buf0 ready
    int cur = 0;
    for (int k0 = 0; k0 < p.K; k0 += 32) {
        if (k0 + 32 < p.K) stage(cur ^ 1, k0 + 32);  // async prefetch overlaps MFMA
        const u16* Asc = As + cur * (BM * 32);
        const u16* Bsc = Bs + cur * (BN * 32);
        bf16x8 af[FR], bfv[FC];
#pragma unroll
        for (int mi = 0; mi < FR; mi++)
            af[mi] = *(const bf16x8*)(Asc + (wm * FR + mi) * 512 + quad * 128 + cn * 8);
#pragma unroll
        for (int ni = 0; ni < FC; ni++)
            bfv[ni] = *(const bf16x8*)(Bsc + (wn * FC + ni) * 512 + quad * 128 + cn * 8);
#pragma unroll
        for (int mi = 0; mi < FR; mi++)
#pragma unroll
            for (int ni = 0; ni < FC; ni++)
                acc[mi][ni] = __builtin_amdgcn_mfma_f32_16x16x32_bf16(
                    af[mi], bfv[ni], acc[mi][ni], 0, 0, 0);
        __syncthreads();  // post-MFMA drain
        cur ^= 1;
    }

    if constexpr (MODE == 4) {
#pragma unroll
        for (int mi = 0; mi < FR; mi++) {
#pragma unroll
            for (int ni = 0; ni < FC; ni++) {
#pragma unroll
                for (int r = 0; r < 4; r++) {
                    int row = m0 + (wm * FR + mi) * 16 + quad * 4 + r;
                    int col = n0 + (wn * FC + ni) * 16 + cn;
                    float v = acc[mi][ni][r];
                    int h = col >> 6, d = col & 63;
                    if (col < 512)
                        p.Q[((long)h * 16384 + row) * 64 + d] = f2b(v * 0.125f);
                    else if (col < 1024)
                        p.Kb[((long)(h - 8) * 16384 + row) * 64 + d] = f2b(v);
                    else
                        p.V[((long)(h - 16) * 16384 + row) * 64 + d] = f2b(v);
                }
            }
        }
    } else {
        float* C = p.C + (long)batch * p.sC;
#pragma unroll
        for (int mi = 0; mi < FR; mi++) {
#pragma unroll
            for (int ni = 0; ni < FC; ni++) {
#pragma unroll
                for (int r = 0; r < 4; r++) {
                    int row = m0 + (wm * FR + mi) * 16 + quad * 4 + r;
                    int col = n0 + (wn * FC + ni) * 16 + cn;
                    float v = acc[mi][ni][r];
                    if (MODE == 0) {
                        C[(long)row * p.ldc + col] = v;
                    } else if (MODE == 1) {
                        C[(long)row * p.ldc + col] = fmaxf(v + p.bias[col], 0.f);
                    } else if (MODE == 2) {
                        C[(long)row * p.ldc + col] += v + p.bias[col];
                    }
                }
            }
        }
    }
}

template <int BM, int BN, int MODE>
static void launch_mgemm(hipStream_t st, GP p, int M, int N, int batch) {
    p.tilesN = N / BN;
    dim3 grid((M / BM) * (N / BN), batch);
    mgemm<BM, BN, MODE><<<grid, 256, 0, st>>>(p);
}

// ================= fused sim3 flash: O_partial = softmax-split(QL K^T) V ======
// 512 threads / 8 waves per block; each wave owns 32 QL rows. 2+ waves/SIMD.
__global__ __launch_bounds__(512) void flash_a3v(
    const u16* __restrict__ QLb, const u16* __restrict__ Kb,
    const u16* __restrict__ VT, float* __restrict__ PART) {
    __shared__ u16 QLs[16384] __attribute__((aligned(16)));  // 16rc x 2kc chunks
    __shared__ u16 Ks[4096] __attribute__((aligned(16)));    // 4rc x 2kc
    __shared__ u16 Vs[4096] __attribute__((aligned(16)));    // 4dc x 2kc
    __shared__ u16 Ps[16384] __attribute__((aligned(16)));   // per-wave 2mi x 2kc
    int tid = threadIdx.x, lane = tid & 63, w = tid >> 6;    // w in 0..7
    int head = blockIdx.y, split = blockIdx.x;
    const u16* QLh = QLb + (long)head * 256 * 64;
    const u16* Kh = Kb + ((long)head * 16384 + split * 512) * 64;
    const u16* Vh = VT + (long)head * 64 * 16384 + split * 512;
    int quad = lane >> 4, cn = lane & 15;
    int lr = lane & 15, lc = (lane >> 4) << 3;

    for (int c = w; c < 32; c += 8) {
        int rc = c >> 1, kc = c & 1;
        gl_lds16(QLh + (long)(rc * 16 + lr) * 64 + kc * 32 + lc, QLs + c * 512 + lane * 8);
    }
    __syncthreads();
    bf16x8 qf[2][2];
#pragma unroll
    for (int mi = 0; mi < 2; mi++)
#pragma unroll
        for (int kc = 0; kc < 2; kc++)
            qf[mi][kc] = *(const bf16x8*)(QLs + ((w * 2 + mi) * 2 + kc) * 512 +
                                          quad * 128 + cn * 8);

    f32x4 Oacc[2][4];
    float m_i[2][4], l_i[2][4];
#pragma unroll
    for (int i = 0; i < 2; i++)
#pragma unroll
        for (int j = 0; j < 4; j++) {
            Oacc[i][j] = (f32x4){0.f, 0.f, 0.f, 0.f};
            m_i[i][j] = -1e30f;
            l_i[i][j] = 0.f;
        }

    for (int t = 0; t < 8; t++) {
        {   // each of the 8 waves stages one K chunk and one V chunk
            int i = w;
            int rc = i >> 1, kc = i & 1;
            gl_lds16(Kh + (long)(t * 64 + rc * 16 + lr) * 64 + kc * 32 + lc,
                     Ks + i * 512 + lane * 8);
            gl_lds16(Vh + (long)(rc * 16 + lr) * 16384 + t * 64 + kc * 32 + lc,
                     Vs + i * 512 + lane * 8);
        }
        __syncthreads();
        f32x4 s[2][4];
#pragma unroll
        for (int i = 0; i < 2; i++)
#pragma unroll
            for (int j = 0; j < 4; j++) s[i][j] = (f32x4){0.f, 0.f, 0.f, 0.f};
#pragma unroll
        for (int kc = 0; kc < 2; kc++) {
            bf16x8 kf[4];
#pragma unroll
            for (int ni = 0; ni < 4; ni++)
                kf[ni] = *(const bf16x8*)(Ks + (ni * 2 + kc) * 512 + quad * 128 + cn * 8);
#pragma unroll
            for (int mi = 0; mi < 2; mi++)
#pragma unroll
                for (int ni = 0; ni < 4; ni++)
                    s[mi][ni] = __builtin_amdgcn_mfma_f32_16x16x32_bf16(
                        qf[mi][kc], kf[ni], s[mi][ni], 0, 0, 0);
        }
        // online softmax per row (mi, r); write P bf16 to this wave's Ps region
#pragma unroll
        for (int mi = 0; mi < 2; mi++) {
#pragma unroll
            for (int r = 0; r < 4; r++) {
                float mx = fmaxf(fmaxf(s[mi][0][r], s[mi][1][r]),
                                 fmaxf(s[mi][2][r], s[mi][3][r]));
                mx = fmaxf(mx, __shfl_xor(mx, 1));
                mx = fmaxf(mx, __shfl_xor(mx, 2));
                mx = fmaxf(mx, __shfl_xor(mx, 4));
                mx = fmaxf(mx, __shfl_xor(mx, 8));
                float mold = m_i[mi][r];
                float mnew = fmaxf(mold, mx);
                float alpha = __expf(mold - mnew);
                m_i[mi][r] = mnew;
                float sum = 0.f;
#pragma unroll
                for (int ni = 0; ni < 4; ni++) {
                    float e = __expf(s[mi][ni][r] - mnew);
                    sum += e;
                    int col = ni * 16 + cn;
                    Ps[w * 2048 + (mi * 2 + (col >> 5)) * 512 + ((col >> 3) & 3) * 128 +
                       (quad * 4 + r) * 8 + (col & 7)] = f2b(e);
                    Oacc[mi][ni][r] *= alpha;
                }
                sum += __shfl_xor(sum, 1);
                sum += __shfl_xor(sum, 2);
                sum += __shfl_xor(sum, 4);
                sum += __shfl_xor(sum, 8);
                l_i[mi][r] = l_i[mi][r] * alpha + sum;
            }
        }
        __syncthreads();
        // PV: O += P @ V
#pragma unroll
        for (int kc = 0; kc < 2; kc++) {
            bf16x8 vf[4], pf[2];
#pragma unroll
            for (int nd = 0; nd < 4; nd++)
                vf[nd] = *(const bf16x8*)(Vs + (nd * 2 + kc) * 512 + quad * 128 + cn * 8);
#pragma unroll
            for (int mi = 0; mi < 2; mi++)
                pf[mi] = *(const bf16x8*)(Ps + w * 2048 + (mi * 2 + kc) * 512 +
                                          quad * 128 + cn * 8);
#pragma unroll
            for (int mi = 0; mi < 2; mi++)
#pragma unroll
                for (int nd = 0; nd < 4; nd++)
                    Oacc[mi][nd] = __builtin_amdgcn_mfma_f32_16x16x32_bf16(
                        pf[mi], vf[nd], Oacc[mi][nd], 0, 0, 0);
        }
        __syncthreads();
    }
    float* base = PART + ((long)head * 32 + split) * 16896;
#pragma unroll
    for (int mi = 0; mi < 2; mi++) {
#pragma unroll
        for (int r = 0; r < 4; r++) {
            int row = w * 32 + mi * 16 + quad * 4 + r;
            if (cn == 0) {
                base[row] = m_i[mi][r];
                base[256 + row] = l_i[mi][r];
            }
#pragma unroll
            for (int ni = 0; ni < 4; ni++)
                base[512 + row * 64 + ni * 16 + cn] = Oacc[mi][ni][r];
        }
    }
}

// combine partials: O[h][row][d] = sum_b exp(m_b-m) O_b / sum_b exp(m_b-m) l_b
__global__ __launch_bounds__(256) void a3v_combine(const float* __restrict__ PART,
                                                   float* __restrict__ O) {
    int head = blockIdx.x, rg = blockIdx.y;
    int t = threadIdx.x;
    int rl = t >> 6, d = t & 63;
    int row = rg * 4 + rl;
    const float* ph = PART + (long)head * 32 * 16896;
    float m = -1e30f;
#pragma unroll 8
    for (int b = 0; b < 32; b++) m = fmaxf(m, ph[b * 16896 + row]);
    float l = 0.f, o = 0.f;
#pragma unroll 8
    for (int b = 0; b < 32; b++) {
        float a = __expf(ph[b * 16896 + row] - m);
        l += a * ph[b * 16896 + 256 + row];
        o += a * ph[b * 16896 + 512 + row * 64 + d];
    }
    O[((long)head * 256 + row) * 64 + d] = o / l;
}

// ================= fused sim1 -> softmax -> @W2 -> +conv -> bf16 ==============
// Round-6 proven version (conv input from precomputed LNA; r11 in-kernel conv
// fusion caused 8-way LDS bank conflicts and regressed 190us/dispatch).
__global__ __launch_bounds__(256) void attn1_fused(
    const u16* __restrict__ Qb, const u16* __restrict__ KLb,
    const u16* __restrict__ W2T, const float* __restrict__ CONV,
    u16* __restrict__ OUTb) {
    __shared__ u16 lds[32768] __attribute__((aligned(16)));
    u16* Qs = lds;
    u16* KLs = lds + 4096;
    u16* Ps = lds;
    u16* W2s = lds + 16384;
    int tid = threadIdx.x, lane = tid & 63, w = tid >> 6;
    int head = blockIdx.y, n0 = blockIdx.x * 64;
    int quad = lane >> 4, cn = lane & 15;
    int lr = lane & 15, lc = (lane >> 4) << 3;
    const u16* Qh = Qb + (long)head * 16384 * 64;
    const u16* KLh = KLb + (long)head * 256 * 64;
    const u16* W2h = W2T + (long)head * 64 * 256;
#pragma unroll
    for (int c = 0; c < 2; c++)
        gl_lds16(Qh + (long)(n0 + w * 16 + lr) * 64 + c * 32 + lc,
                 Qs + c * 2048 + w * 512 + lane * 8);
#pragma unroll
    for (int c = 0; c < 2; c++)
#pragma unroll
        for (int rg = 0; rg < 4; rg++) {
            int chunk = rg * 4 + w;
            gl_lds16(KLh + (long)(chunk * 16 + lr) * 64 + c * 32 + lc,
                     KLs + c * 8192 + chunk * 512 + lane * 8);
        }
    __syncthreads();
    f32x4 acc[16];
#pragma unroll
    for (int i = 0; i < 16; i++) acc[i] = (f32x4){0.f, 0.f, 0.f, 0.f};
#pragma unroll
    for (int c = 0; c < 2; c++) {
        bf16x8 af = *(const bf16x8*)(Qs + c * 2048 + w * 512 + quad * 128 + cn * 8);
#pragma unroll
        for (int ni = 0; ni < 16; ni++) {
            bf16x8 bfv = *(const bf16x8*)(KLs + c * 8192 + ni * 512 + quad * 128 + cn * 8);
            acc[ni] = __builtin_amdgcn_mfma_f32_16x16x32_bf16(af, bfv, acc[ni], 0, 0, 0);
        }
    }
    __syncthreads();
#pragma unroll
    for (int r = 0; r < 4; r++) {
        float mx = -1e30f;
#pragma unroll
        for (int ni = 0; ni < 16; ni++) mx = fmaxf(mx, acc[ni][r]);
        mx = fmaxf(mx, __shfl_xor(mx, 1));
        mx = fmaxf(mx, __shfl_xor(mx, 2));
        mx = fmaxf(mx, __shfl_xor(mx, 4));
        mx = fmaxf(mx, __shfl_xor(mx, 8));
        float e[16];
        float s = 0.f;
#pragma unroll
        for (int ni = 0; ni < 16; ni++) {
            e[ni] = __expf(acc[ni][r] - mx);
            s += e[ni];
        }
        s += __shfl_xor(s, 1);
        s += __shfl_xor(s, 2);
        s += __shfl_xor(s, 4);
        s += __shfl_xor(s, 8);
        float inv = 1.f / s;
        int prow = w * 16 + quad * 4 + r;
#pragma unroll
        for (int ni = 0; ni < 16; ni++) {
            int k = ni * 16 + cn;
            Ps[(k >> 5) * 2048 + ((k >> 3) & 3) * 512 + prow * 8 + (k & 7)] =
                f2b(e[ni] * inv);
        }
    }
#pragma unroll
    for (int c = 0; c < 8; c++)
        gl_lds16(W2h + (long)(w * 16 + lr) * 256 + c * 32 + lc,
                 W2s + c * 2048 + w * 512 + lane * 8);
    __syncthreads();
    f32x4 acc2[4];
#pragma unroll
    for (int i = 0; i < 4; i++) acc2[i] = (f32x4){0.f, 0.f, 0.f, 0.f};
#pragma unroll
    for (int c = 0; c < 8; c++) {
        bf16x8 af = *(const bf16x8*)(Ps + c * 2048 + quad * 512 + (w * 16 + cn) * 8);
#pragma unroll
        for (int ni = 0; ni < 4; ni++) {
            bf16x8 bfv = *(const bf16x8*)(W2s + c * 2048 + ni * 512 + quad * 128 + cn * 8);
            acc2[ni] = __builtin_amdgcn_mfma_f32_16x16x32_bf16(af, bfv, acc2[ni], 0, 0, 0);
        }
    }
#pragma unroll
    for (int ni = 0; ni < 4; ni++)
#pragma unroll
        for (int r = 0; r < 4; r++) {
            int row = n0 + w * 16 + quad * 4 + r;
            long idx = (long)row * 512 + head * 64 + ni * 16 + cn;
            OUTb[idx] = f2b(CONV[idx] + acc2[ni][r]);
        }
}

// ================= fp32 tile GEMM (W2T = (z @ a3v) transposed bf16) ============
// f2b + transposed store fused (w2t_kernel deleted; fp32 W2 buffer dead).
// Same acc value through f2b -> bit-identical. Verified passing in r11.
#define TILE 64
#define KT 16
#define LDP (TILE + 4)
__global__ __launch_bounds__(256) void gemm32t_kernel(
    const float* __restrict__ A, const float* __restrict__ B, u16* __restrict__ CT,
    int M, int N, int K, int lda, int ldb,
    long sA, long sB, int tilesN) {
    int tm = blockIdx.x / tilesN, tn = blockIdx.x % tilesN;
    int batch = blockIdx.y;
    A += (long)batch * sA; B += (long)batch * sB;
    int row0 = tm * TILE, col0 = tn * TILE;
    __shared__ float As[KT][LDP];
    __shared__ float Bs[KT][LDP];
    int t = threadIdx.x;
    int tx = t & 15, ty = t >> 4;
    float acc[4][4] = {{0.f}};
    int aRow = t >> 2, aK = (t & 3) << 2;
    int bN = t & 63, bK = (t >> 6) << 2;
    for (int k0 = 0; k0 < K; k0 += KT) {
        {
            int r = row0 + aRow;
            float4 av = make_float4(0.f, 0.f, 0.f, 0.f);
            if (r < M) av = *(const float4*)(A + (long)r * lda + k0 + aK);
            As[aK][aRow] = av.x; As[aK + 1][aRow] = av.y;
            As[aK + 2][aRow] = av.z; As[aK + 3][aRow] = av.w;
        }
        {
            const float* bp = B + (long)(k0 + bK) * ldb + col0 + bN;
            bool ok = col0 + bN < N;
#pragma unroll
            for (int j = 0; j < 4; j++) Bs[bK + j][bN] = ok ? bp[(long)j * ldb] : 0.f;
        }
        __syncthreads();
#pragma unroll
        for (int kk = 0; kk < KT; kk++) {
            float4 a = *(const float4*)&As[kk][ty << 2];
            float4 b = *(const float4*)&Bs[kk][tx << 2];
            acc[0][0] += a.x * b.x; acc[0][1] += a.x * b.y; acc[0][2] += a.x * b.z; acc[0][3] += a.x * b.w;
            acc[1][0] += a.y * b.x; acc[1][1] += a.y * b.y; acc[1][2] += a.y * b.z; acc[1][3] += a.y * b.w;
            acc[2][0] += a.z * b.x; acc[2][1] += a.z * b.y; acc[2][2] += a.z * b.z; acc[2][3] += a.z * b.w;
            acc[3][0] += a.w * b.x; acc[3][1] += a.w * b.y; acc[3][2] += a.w * b.z; acc[3][3] += a.w * b.w;
        }
        __syncthreads();
    }
    // CT[batch][col][row] = f2b(acc)  (stride: batch M*N, col M)
#pragma unroll
    for (int i = 0; i < 4; i++) {
        int row = row0 + (ty << 2) + i;
        if (row >= M) continue;
#pragma unroll
        for (int j = 0; j < 4; j++) {
            int col = col0 + (tx << 2) + j;
            if (col >= N) continue;
            CT[(long)batch * M * N + (long)col * M + row] = f2b(acc[i][j]);
        }
    }
}
static void gemm32t(hipStream_t st, int M, int N, int K,
                    const float* A, int lda, long sA,
                    const float* B, int ldb, long sB,
                    u16* CT, int batch) {
    int tilesM = (M + TILE - 1) / TILE, tilesN = (N + TILE - 1) / TILE;
    dim3 grid(tilesM * tilesN, batch);
    gemm32t_kernel<<<grid, 256, 0, st>>>(A, B, CT, M, N, K, lda, ldb, sA, sB, tilesN);
}

// ================= pinv fused chain (fp32; also emits z^T bf16) ================
// Register version (round-2 proven): per-thread row reads are L2-resident with
// high TLP. LDS-tiling (-13us/launch) and 512t widening (2x read traffic) both
// measured as regressions; keep this form.
__global__ __launch_bounds__(256) void pinv_chain(const float* __restrict__ xz,
                                                  const float* __restrict__ z,
                                                  float* __restrict__ zn,
                                                  u16* __restrict__ znT) {
    int h = blockIdx.y, c0 = blockIdx.x * 8;
    const float* X = xz + (long)h * 65536;
    const float* Z = z + (long)h * 65536;
    __shared__ float ta[256][8];
    __shared__ float tb[256][8];
    int t = threadIdx.x;
    const float4* X4 = (const float4*)(X + t * 256);
    const float4* Z4 = (const float4*)(Z + t * 256);
    float acc[8];
#pragma unroll
    for (int j = 0; j < 8; j++)
        ta[t][j] = ((t == c0 + j) ? 7.f : 0.f) - X[t * 256 + c0 + j];
    __syncthreads();
#pragma unroll
    for (int j = 0; j < 8; j++) acc[j] = 0.f;
    for (int k4 = 0; k4 < 64; k4++) {
        float4 xv = X4[k4];
#pragma unroll
        for (int j = 0; j < 8; j++)
            acc[j] += xv.x * ta[k4 * 4][j] + xv.y * ta[k4 * 4 + 1][j] +
                      xv.z * ta[k4 * 4 + 2][j] + xv.w * ta[k4 * 4 + 3][j];
    }
#pragma unroll
    for (int j = 0; j < 8; j++)
        tb[t][j] = ((t == c0 + j) ? 15.f : 0.f) - acc[j];
    __syncthreads();
#pragma unroll
    for (int j = 0; j < 8; j++) acc[j] = 0.f;
    for (int k4 = 0; k4 < 64; k4++) {
        float4 xv = X4[k4];
#pragma unroll
        for (int j = 0; j < 8; j++)
            acc[j] += xv.x * tb[k4 * 4][j] + xv.y * tb[k4 * 4 + 1][j] +
                      xv.z * tb[k4 * 4 + 2][j] + xv.w * tb[k4 * 4 + 3][j];
    }
    __syncthreads();
#pragma unroll
    for (int j = 0; j < 8; j++)
        ta[t][j] = ((t == c0 + j) ? 13.f : 0.f) - acc[j];
    __syncthreads();
#pragma unroll
    for (int j = 0; j < 8; j++) acc[j] = 0.f;
    for (int k4 = 0; k4 < 64; k4++) {
        float4 zv = Z4[k4];
#pragma unroll
        for (int j = 0; j < 8; j++)
            acc[j] += zv.x * ta[k4 * 4][j] + zv.y * ta[k4 * 4 + 1][j] +
                      zv.z * ta[k4 * 4 + 2][j] + zv.w * ta[k4 * 4 + 3][j];
    }
#pragma unroll
    for (int j = 0; j < 8; j++) {
        float v = 0.25f * acc[j];
        zn[(long)h * 65536 + t * 256 + c0 + j] = v;
        znT[(long)h * 65536 + (c0 + j) * 256 + t] = f2b(v);
    }
}

// ================= layernorm / softmax / misc =================================
__global__ __launch_bounds__(256) void layernorm_bf16(
    const float* __restrict__ x, const float* __restrict__ g,
    const float* __restrict__ b, u16* __restrict__ y) {
    __shared__ float sm[4];
    long base = (long)blockIdx.x * 512;
    int t = threadIdx.x;
    float v0 = x[base + t], v1 = x[base + 256 + t];
    float s = wred_sum(v0 + v1);
    if ((t & 63) == 0) sm[t >> 6] = s;
    __syncthreads();
    float mu = (sm[0] + sm[1] + sm[2] + sm[3]) * (1.f / 512.f);
    __syncthreads();
    float d0 = v0 - mu, d1 = v1 - mu;
    float q = wred_sum(d0 * d0 + d1 * d1);
    if ((t & 63) == 0) sm[t >> 6] = q;
    __syncthreads();
    float var = (sm[0] + sm[1] + sm[2] + sm[3]) * (1.f / 512.f);
    float rstd = rsqrtf(var + 1e-5f);
    y[base + t] = f2b(d0 * rstd * g[t] + b[t]);
    y[base + 256 + t] = f2b(d1 * rstd * g[256 + t] + b[256 + t]);
}

// softmax fp32 in place (ncols=256); bf16 copy; fused |col|-sum accumulation.
// a2 is post-softmax (positive, row-sum==1) so reference's max(col)==1 exactly;
// only the column sums are needed for the pinv scale.
__global__ __launch_bounds__(256) void softmax_rows_cs(float* __restrict__ data,
                                                       u16* __restrict__ outb,
                                                       float* __restrict__ colsum) {
    __shared__ float sm[4];
    float* row = data + (long)blockIdx.x * 256;
    u16* rowb = outb + (long)blockIdx.x * 256;
    int h = blockIdx.x >> 8;
    int t = threadIdx.x;
    float v0 = row[t];
    float m = wred_max(v0);
    if ((t & 63) == 0) sm[t >> 6] = m;
    __syncthreads();
    m = fmaxf(fmaxf(sm[0], sm[1]), fmaxf(sm[2], sm[3]));
    __syncthreads();
    float e = __expf(v0 - m);
    float s = wred_sum(e);
    if ((t & 63) == 0) sm[t >> 6] = s;
    __syncthreads();
    s = sm[0] + sm[1] + sm[2] + sm[3];
    float v = e / s;
    row[t] = v;
    rowb[t] = f2b(v);
    atomicAdd(&colsum[h * 256 + t], v);
}

__global__ void cls_copy(const float* __restrict__ cls, float* __restrict__ X) {
    X[threadIdx.x] = cls[threadIdx.x];
}
__global__ void build_hb(const float* __restrict__ h, u16* __restrict__ dst) {
    long idx = (long)blockIdx.x * 256 + threadIdx.x;
    long row = idx >> 10;
    int col = (int)(idx & 1023);
    float v = (row == 0) ? 0.f : h[((row - 1) << 10) + col];
    dst[idx] = f2b(v);
}
// LDS-tiled fp32 -> bf16 transpose: coalesced loads and coalesced stores.
__global__ __launch_bounds__(256) void transpose_to_bf16_t(
    const float* __restrict__ src, u16* __restrict__ dst, int R, int C) {
    __shared__ u16 tile[64][65];
    int tilesC = C >> 6;
    int rt = blockIdx.x / tilesC, ct = blockIdx.x % tilesC;
    int t = threadIdx.x, w = t >> 6, lane = t & 63;
    const float* sp = src + (long)(rt * 64) * C + ct * 64;
#pragma unroll
    for (int k = 0; k < 16; k++) {
        int r = w * 16 + k;
        tile[lane][r] = f2b(sp[(long)r * C + lane]);
    }
    __syncthreads();
    u16* dp = dst + (long)(ct * 64) * R + rt * 64;
#pragma unroll
    for (int k = 0; k < 16; k++) {
        int c = w * 16 + k;
        dp[(long)c * R + lane] = tile[c][lane];
    }
}
__global__ __launch_bounds__(256) void transpose_v(const u16* __restrict__ Vb,
                                                   u16* __restrict__ VT) {
    __shared__ u16 tile[64][68];
    int h = blockIdx.y, n0 = blockIdx.x * 64;
    int t = threadIdx.x;
    int i = t >> 2, seg = t & 3;
    const u16* src = Vb + ((long)h * 16384 + n0 + i) * 64 + seg * 16;
#pragma unroll
    for (int j = 0; j < 16; j++) tile[seg * 16 + j][i] = src[j];
    __syncthreads();
    u16* dst = VT + ((long)h * 64 + i) * 16384 + n0 + seg * 16;
#pragma unroll
    for (int j = 0; j < 16; j++) dst[j] = tile[i][seg * 16 + j];
}
__global__ void landmarks_b(const u16* __restrict__ Qb, const u16* __restrict__ Kb,
                            u16* __restrict__ QLb, u16* __restrict__ KLb) {
    int h = blockIdx.x >> 8, j = blockIdx.x & 255, d = threadIdx.x;
    const u16* qb = Qb + ((long)h * 16384 + j * 64) * 64 + d;
    const u16* kb = Kb + ((long)h * 16384 + j * 64) * 64 + d;
    float sq = 0.f, sk = 0.f;
    for (int tk = 0; tk < 64; ++tk) {
        sq += b2f(qb[tk * 64]);
        sk += b2f(kb[tk * 64]);
    }
    QLb[((h << 8) + j) * 64 + d] = f2b(sq * (1.f / 64.f));
    KLb[((h << 8) + j) * 64 + d] = f2b(sk * (1.f / 64.f));
}

// finalize pinv scale: maxes[0]=1 (softmax row-sums), maxes[1]=max column sum.
__global__ __launch_bounds__(256) void pinv_absmax_fin(const float* __restrict__ colsum,
                                                       float* __restrict__ maxes) {
    __shared__ float sm[4];
    int t = threadIdx.x;
    float m = 0.f;
#pragma unroll
    for (int h = 0; h < 8; h++) m = fmaxf(m, colsum[h * 256 + t]);
    m = wred_max(m);
    if ((t & 63) == 0) sm[t >> 6] = m;
    __syncthreads();
    if (t == 0) {
        maxes[0] = 1.0f;
        maxes[1] = fmaxf(fmaxf(sm[0], sm[1]), fmaxf(sm[2], sm[3]));
    }
}

// z0 = a2^T * s (fp32) and z0^T bf16 (= a2 * s)
__global__ void pinv_init(const float* __restrict__ a2, const float* __restrict__ maxes,
                          float* __restrict__ z, u16* __restrict__ zT) {
    long idx = (long)blockIdx.x * 256 + threadIdx.x;
    int h = (int)(idx >> 16);
    int rem = (int)(idx & 65535);
    int i = rem >> 8, j = rem & 255;
    float inv = 1.f / (maxes[0] * maxes[1]);
    float v = a2[((long)h << 16) + (j << 8) + i] * inv;
    z[idx] = v;
    zT[((long)h << 16) + (j << 8) + i] = f2b(v);
}
__global__ __launch_bounds__(256) void conv_kernel(const u16* __restrict__ VT,
                                                   const float* __restrict__ cw,
                                                   float* __restrict__ out) {
    int h = blockIdx.y;
    int n0 = blockIdx.x * 64;
    __shared__ float vt[64][97];
    int t = threadIdx.x;
    for (int i = t; i < 64 * 96; i += 256) {
        int d = i / 96, j = i % 96;
        int n = n0 - 16 + j;
        float v = 0.f;
        if (n >= 0 && n < 16384) v = b2f(VT[((long)h * 64 + d) * 16384 + n]);
        vt[d][j] = v;
    }
    __syncthreads();
    float w[33];
#pragma unroll
    for (int k = 0; k < 33; k++) w[k] = cw[h * 33 + k];
    int d = t & 63, ty = t >> 6;
    for (int nn = 0; nn < 16; nn++) {
        int nl = ty * 16 + nn;
        float s = 0.f;
#pragma unroll
        for (int k = 0; k < 33; k++) s += w[k] * vt[d][nl + k];
        out[((long)(n0 + nl)) * 512 + h * 64 + d] = s;
    }
}
__global__ __launch_bounds__(256) void final_head(
    const float* __restrict__ X, const float* __restrict__ g, const float* __restrict__ b,
    const float* __restrict__ W, const float* __restrict__ bias, float* __restrict__ out) {
    __shared__ float sm[4];
    __shared__ float ln0[512];
    int t = threadIdx.x;
    float v0 = X[t], v1 = X[256 + t];
    float s = wred_sum(v0 + v1);
    if ((t & 63) == 0) sm[t >> 6] = s;
    __syncthreads();
    float mu = (sm[0] + sm[1] + sm[2] + sm[3]) * (1.f / 512.f);
    __syncthreads();
    float d0 = v0 - mu, d1 = v1 - mu;
    float q = wred_sum(d0 * d0 + d1 * d1);
    if ((t & 63) == 0) sm[t >> 6] = q;
    __syncthreads();
    float rstd = rsqrtf((sm[0] + sm[1] + sm[2] + sm[3]) * (1.f / 512.f) + 1e-5f);
    ln0[t] = d0 * rstd * g[t] + b[t];
    ln0[256 + t] = d1 * rstd * g[256 + t] + b[256 + t];
    __syncthreads();
    int jj = blockIdx.x * 256 + t;
    if (jj < 1000) {
        float acc = bias[jj];
        for (int dd = 0; dd < 512; ++dd) acc += ln0[dd] * W[dd * 1000 + jj];
        out[jj] = acc;
    }
}

// ================= layer driver ================================================
struct Bufs {
    float *X, *LNA, *A2, *Z0, *Z1, *XZ, *O, *MAXES, *COLSUM, *PART;
    u16 *LNb, *Qb, *Kb, *Vb, *VT, *QLb, *KLb, *W2T, *W1T, *QKVWT, *OUTWT;
    u16 *A2b, *ZT0, *ZT1;
};

static void run_layer(hipStream_t st, Bufs& B,
                      const float* ln_g, const float* ln_b, const float* qkv_W,
                      const float* conv_W, const float* out_W, const float* out_b) {
    const int N = 16384, D = 512, H = 8, DH = 64, M = 256;
    GP p{};
    // 1. LN -> bf16
    layernorm_bf16<<<N, 256, 0, st>>>(B.X, ln_g, ln_b, B.LNb);
    // 2. qkv (row-major q/k/v epilogue), then VT transpose
    transpose_to_bf16_t<<<(512 / 64) * (1536 / 64), 256, 0, st>>>(qkv_W, B.QKVWT, 512, 1536);
    p = GP{}; p.A = B.LNb; p.B = B.QKVWT; p.Q = B.Qb; p.Kb = B.Kb; p.V = B.Vb; p.K = 512;
    launch_mgemm<128, 128, 4>(st, p, N, 1536, 1);
    transpose_v<<<dim3(256, 8), 256, 0, st>>>(B.Vb, B.VT);
    // 3. landmarks
    landmarks_b<<<H * M, 64, 0, st>>>(B.Qb, B.Kb, B.QLb, B.KLb);
    // 4. sim2 -> softmax (fp32 + bf16 + colsum) -> pinv
    p = GP{}; p.A = B.QLb; p.B = B.KLb; p.C = B.A2; p.K = DH; p.ldc = M;
    p.sA = (long)M * DH; p.sB = (long)M * DH; p.sC = (long)M * M;
    launch_mgemm<64, 64, 0>(st, p, M, M, H);
    hipMemsetAsync(B.COLSUM, 0, 8 * 256 * 4, st);
    softmax_rows_cs<<<H * M, 256, 0, st>>>(B.A2, B.A2b, B.COLSUM);
    pinv_absmax_fin<<<1, 256, 0, st>>>(B.COLSUM, B.MAXES);
    pinv_init<<<(H * M * M) / 256, 256, 0, st>>>(B.A2, B.MAXES, B.Z0, B.ZT0);
    float* z = B.Z0; float* zn = B.Z1;
    u16* zt = B.ZT0; u16* ztn = B.ZT1;
    for (int it = 0; it < 6; ++it) {
        // XZ = a2 @ z via bf16 MFMA (NT with z^T); 64-tile -> 128 blocks
        p = GP{}; p.A = B.A2b; p.B = zt; p.C = B.XZ; p.K = M; p.ldc = M;
        p.sA = (long)M * M; p.sB = (long)M * M; p.sC = (long)M * M;
        launch_mgemm<64, 64, 0>(st, p, M, M, H);
        pinv_chain<<<dim3(32, 8), 256, 0, st>>>(B.XZ, z, zn, ztn);
        float* t1 = z; z = zn; zn = t1;
        u16* t2 = zt; zt = ztn; ztn = t2;
    }
    // 5. conv residual initializes ATTN (LNA)
    conv_kernel<<<dim3(N / 64, H), 256, 0, st>>>(B.VT, conv_W, B.LNA);
    // 6. fused sim3 flash (split over 32 key-ranges; 512 thr / 8 waves) + combine
    flash_a3v<<<dim3(32, 8), 512, 0, st>>>(B.QLb, B.Kb, B.VT, B.PART);
    a3v_combine<<<dim3(8, 64), 256, 0, st>>>(B.PART, B.O);
    // 7. W2T = (z @ a3v)^T bf16 directly (w2t fused into gemm32t)
    gemm32t(st, M, DH, M, z, M, (long)M * M, B.O, DH, (long)M * DH, B.W2T, H);
    // 8. fused sim1 -> softmax -> @W2 -> +conv -> LNb (bf16)
    attn1_fused<<<dim3(N / 64, H), 256, 0, st>>>(B.Qb, B.KLb, B.W2T, B.LNA, B.LNb);
    // 9. out projection: X += ATTN @ out_W + out_b
    transpose_to_bf16_t<<<(512 / 64) * (512 / 64), 256, 0, st>>>(out_W, B.OUTWT, 512, 512);
    p = GP{}; p.A = B.LNb; p.B = B.OUTWT; p.C = B.X; p.bias = out_b; p.K = D; p.ldc = D;
    launch_mgemm<128, 128, 2>(st, p, N, D, 1);
}

extern "C" void kernel_launch(void* const* d_in, const int* in_sizes, int n_in,
                              void* d_out, int out_size, void* d_ws, size_t ws_size,
                              hipStream_t stream) {
    const float* h_in = (const float*)d_in[0];
    const float* W1 = (const float*)d_in[1];
    const float* b1 = (const float*)d_in[2];
    const float* cls = (const float*)d_in[3];
    const float* ln1_g = (const float*)d_in[4];
    const float* ln1_b = (const float*)d_in[5];
    const float* qkv1_W = (const float*)d_in[6];
    const float* conv1_W = (const float*)d_in[7];
    const float* out1_W = (const float*)d_in[8];
    const float* out1_b = (const float*)d_in[9];
    const float* ln2_g = (const float*)d_in[10];
    const float* ln2_b = (const float*)d_in[11];
    const float* qkv2_W = (const float*)d_in[12];
    const float* conv2_W = (const float*)d_in[13];
    const float* out2_W = (const float*)d_in[14];
    const float* out2_b = (const float*)d_in[15];
    const float* lnf_g = (const float*)d_in[16];
    const float* lnf_b = (const float*)d_in[17];
    const float* fc2_W = (const float*)d_in[18];
    const float* fc2_b = (const float*)d_in[19];
    float* out = (float*)d_out;

    char* wsb = (char*)d_ws;
    size_t off = 0;
    auto alloc = [&](size_t bytes) -> void* {
        void* p = (void*)(wsb + off);
        off += (bytes + 255) & ~(size_t)255;
        return p;
    };
    Bufs B;
    B.X    = (float*)alloc((size_t)16384 * 512 * 4);
    B.LNA  = (float*)alloc((size_t)16384 * 512 * 4);
    B.LNb  = (u16*)alloc((size_t)16384 * 512 * 2);
    B.Qb   = (u16*)alloc((size_t)8 * 16384 * 64 * 2);   // adjacent to Kb: HB alias
    B.Kb   = (u16*)alloc((size_t)8 * 16384 * 64 * 2);
    B.VT   = (u16*)alloc((size_t)8 * 64 * 16384 * 2);
    B.QLb  = (u16*)alloc((size_t)8 * 256 * 64 * 2);
    B.KLb  = (u16*)alloc((size_t)8 * 256 * 64 * 2);
    B.A2   = (float*)alloc((size_t)8 * 256 * 256 * 4);
    B.A2b  = (u16*)alloc((size_t)8 * 256 * 256 * 2);
    B.Z0   = (float*)alloc((size_t)8 * 256 * 256 * 4);
    B.Z1   = (float*)alloc((size_t)8 * 256 * 256 * 4);
    B.ZT0  = (u16*)alloc((size_t)8 * 256 * 256 * 2);
    B.ZT1  = (u16*)alloc((size_t)8 * 256 * 256 * 2);
    B.XZ   = (float*)alloc((size_t)8 * 256 * 256 * 4);
    B.O    = (float*)alloc((size_t)8 * 256 * 64 * 4);
    B.W2T  = (u16*)alloc((size_t)8 * 64 * 256 * 2);
    B.W1T  = (u16*)alloc((size_t)512 * 1024 * 2);
    B.QKVWT = (u16*)alloc((size_t)1536 * 512 * 2);
    B.OUTWT = (u16*)alloc((size_t)512 * 512 * 2);
    B.MAXES = (float*)alloc(256);
    B.COLSUM = (float*)alloc((size_t)8 * 256 * 4);
    // union region: Vb (16 MB, dead after transpose_v) aliases PART (17.3 MB)
    {
        size_t vb = (size_t)8 * 16384 * 64 * 2;
        size_t part = (size_t)8 * 32 * 16896 * 4;
        void* region = alloc(part > vb ? part : vb);
        B.Vb = (u16*)region;
        B.PART = (float*)region;
    }
    if (off > ws_size) return;  // fail loudly (output stays poisoned)

    // fc1: HB (aliases Qb..Kb, 32MB) = [0; h] bf16; X = relu(HB @ W1^T + b1); X[0]=cls
    u16* HB = B.Qb;
    build_hb<<<(16384 * 1024) / 256, 256, 0, stream>>>(h_in, HB);
    transpose_to_bf16_t<<<(1024 / 64) * (512 / 64), 256, 0, stream>>>(W1, B.W1T, 1024, 512);
    {
        GP p{}; p.A = HB; p.B = B.W1T; p.C = B.X; p.bias = b1; p.K = 1024; p.ldc = 512;
        launch_mgemm<128, 128, 1>(stream, p, 16384, 512, 1);
    }
    cls_copy<<<1, 512, 0, stream>>>(cls, B.X);

    run_layer(stream, B, ln1_g, ln1_b, qkv1_W, conv1_W, out1_W, out1_b);
    run_layer(stream, B, ln2_g, ln2_b, qkv2_W, conv2_W, out2_W, out2_b);

    final_head<<<4, 256, 0, stream>>>(B.X, lnf_g, lnf_b, fc2_W, fc2_b, out);
}